// Round 1
// 6635.137 us; speedup vs baseline: 1.6087x; 1.6087x over previous
//
#include <hip/hip_runtime.h>
#include <stdint.h>

typedef __attribute__((ext_vector_type(8))) short short8;
typedef __attribute__((ext_vector_type(4))) float float4v;
typedef __attribute__((ext_vector_type(4))) unsigned short ushort4v;

constexpr int T = 128;
constexpr int NB = 512;          // batch
constexpr int NCH = 16;          // row chains (32 rows each)
constexpr int CBLK = 12;         // blocks per chain (feature-column parallelism)

__device__ __forceinline__ float bf2f(ushort u) {
  union { float f; uint32_t i; } v; v.i = ((uint32_t)u) << 16; return v.f;
}
__device__ __forceinline__ ushort f2bf(float f) {
  union { float f; uint32_t i; } v; v.f = f;
  uint32_t i = v.i;
  uint32_t r = i + 0x7FFFu + ((i >> 16) & 1u);
  return (ushort)(r >> 16);
}

// Coherent (cache-bypassing, sc0 sc1) accessors for cross-block h state.
__device__ __forceinline__ float coh_load(const float* p) {
  return __hip_atomic_load(const_cast<float*>(p), __ATOMIC_RELAXED,
                           __HIP_MEMORY_SCOPE_SYSTEM);
}
__device__ __forceinline__ void coh_store(float* p, float v) {
  __hip_atomic_store(p, v, __ATOMIC_RELAXED, __HIP_MEMORY_SCOPE_SYSTEM);
}

// ---------------------------------------------------------------------------
// Pack f32 weights (optionally masked) into SPLIT bf16 MFMA B-fragment layout.
// ---------------------------------------------------------------------------
__global__ __launch_bounds__(256) void pack_w(const float* __restrict__ W,
                                              const float* __restrict__ mask,
                                              ushort* __restrict__ out, int loOff,
                                              int NN, int IT, int NT, int KB) {
  int idx = blockIdx.x * 256 + threadIdx.x;
  int total = KB * NT * 512;
  if (idx >= total) return;
  int jj   = idx & 7;
  int lane = (idx >> 3) & 63;
  int nt   = (idx >> 9) % NT;
  int kb   = (idx >> 9) / NT;
  int n = nt * 16 + (lane & 15);
  int k = kb * 32 + (lane >> 4) * 8 + jj;
  float v = 0.f;
  if (n < NN && k < IT) {
    v = W[(size_t)n * IT + k];
    if (mask) v *= mask[(size_t)n * IT + k];
  }
  ushort hi = f2bf(v);
  out[idx] = hi;
  out[loOff + idx] = f2bf(v - bf2f(hi));
}

// ---------------------------------------------------------------------------
// One CfC cell tile job: 32 rows x (16*NTW) neurons, all 4 matrices (1/wave),
// split-bf16 3-term MFMA. Depth-4 software pipeline with RAW s_barrier
// (no vmcnt drain!) so up to 4 k-steps of A+B loads stay in flight.
// A-tile double-buffered in LDS -> single barrier per k-step.
// ---------------------------------------------------------------------------
template <int NTW, bool C0, bool C1, int KB>
__device__ __forceinline__ void cell_job(
    ushort* __restrict__ Ah, ushort* __restrict__ Al, float* __restrict__ Acc,
    const float* __restrict__ a0, int a0s, const float* __restrict__ a1, int a1s,
    int SEG1, int IT, int NT, int loOff,
    const ushort* const* __restrict__ wf4, const float* const* __restrict__ bias4,
    int NN, float* __restrict__ hout, float* __restrict__ out2,
    int b0, int ntp) {
  constexpr int PD = 4;   // pipeline depth (must be even; KB>=PD holds here)
  const int tid  = threadIdx.x;
  const int wave = tid >> 6, lane = tid & 63, quad = lane >> 4, l16 = lane & 15;
  const ushort* wfq = wf4[wave];
  const int nt0 = ntp * NTW;
  const int n0  = nt0 * 16;

  float4v acc[2][NTW];
#pragma unroll
  for (int i = 0; i < 2; i++)
#pragma unroll
    for (int w = 0; w < NTW; w++) acc[i][w] = float4v{0.f, 0.f, 0.f, 0.f};

  const int sm = tid >> 3;        // staging row 0..31
  const int sk = (tid & 7) * 4;   // staging col base
  const size_t ar0 = (size_t)(b0 + sm) * a0s;
  const size_t ar1 = (size_t)(b0 + sm) * a1s;

  short8 cbh[PD][NTW], cbl[PD][NTW];
  float4v av[PD];

  auto loadB = [&](int kb, short8* bh, short8* bl) {
#pragma unroll
    for (int w = 0; w < NTW; w++) {
      const size_t fo = ((size_t)(kb * NT + nt0 + w) * 64 + lane) * 8;
      bh[w] = *(const short8*)(wfq + fo);
      bl[w] = *(const short8*)(wfq + loOff + fo);
    }
  };
  auto loadA = [&](int kb) -> float4v {
    const int kg0 = kb * 32 + sk;
    float4v r;
    if (!C0 && kg0 + 3 < SEG1) {           // vector path (x segment, cached)
      r = *(const float4v*)(a0 + ar0 + kg0);
    } else {
#pragma unroll
      for (int e = 0; e < 4; e++) {
        int kg = kg0 + e;
        float v = 0.f;
        if (kg < SEG1)    v = C0 ? coh_load(a0 + ar0 + kg) : a0[ar0 + kg];
        else if (kg < IT) v = C1 ? coh_load(a1 + ar1 + (kg - SEG1)) : a1[ar1 + (kg - SEG1)];
        r[e] = v;
      }
    }
    return r;
  };

  // prologue: fill all PD slots (loads overlap; first consumed ~latency later)
#pragma unroll
  for (int i = 0; i < PD; i++) { av[i] = loadA(i); loadB(i, cbh[i], cbl[i]); }

  for (int kb0 = 0; kb0 < KB; kb0 += PD) {
#pragma unroll
    for (int u = 0; u < PD; u++) {
      const int kb = kb0 + u;
      if ((KB % PD) && kb >= KB) continue;     // folds away when KB%PD==0
      const int ab = (u & 1) * 1280;           // LDS A-tile double buffer

      // stage A slot u (compiler inserts the minimal counted vmcnt wait)
      ushort4v hi4, lo4;
#pragma unroll
      for (int e = 0; e < 4; e++) {
        float v = av[u][e];
        ushort hi = f2bf(v);
        hi4[e] = hi;
        lo4[e] = f2bf(v - bf2f(hi));
      }
      *(ushort4v*)(Ah + ab + sm * 40 + sk) = hi4;
      *(ushort4v*)(Al + ab + sm * 40 + sk) = lo4;
      // LDS writes visible, then barrier. NO vmcnt drain: prefetches for
      // slots u+1..u+3 stay in flight across the barrier.
      asm volatile("s_waitcnt lgkmcnt(0)\n\ts_barrier" ::: "memory");

#pragma unroll
      for (int mt = 0; mt < 2; mt++) {
        short8 ah = *(const short8*)&Ah[ab + (mt * 16 + l16) * 40 + quad * 8];
        short8 al = *(const short8*)&Al[ab + (mt * 16 + l16) * 40 + quad * 8];
#pragma unroll
        for (int w = 0; w < NTW; w++) {
          acc[mt][w] = __builtin_amdgcn_mfma_f32_16x16x32_bf16(ah, cbh[u][w], acc[mt][w], 0, 0, 0);
          acc[mt][w] = __builtin_amdgcn_mfma_f32_16x16x32_bf16(al, cbh[u][w], acc[mt][w], 0, 0, 0);
          acc[mt][w] = __builtin_amdgcn_mfma_f32_16x16x32_bf16(ah, cbl[u][w], acc[mt][w], 0, 0, 0);
        }
      }
      // refill slot u for kb+PD (registers just consumed above)
      if (kb + PD < KB) { av[u] = loadA(kb + PD); loadB(kb + PD, cbh[u], cbl[u]); }
      // No second barrier needed: next k-step writes the OTHER A buffer;
      // this buffer is rewritten only at kb+2, which is after barrier(kb+1).
    }
  }

  // spill accumulators to LDS for cross-wave (cross-matrix) combine
#pragma unroll
  for (int mt = 0; mt < 2; mt++)
#pragma unroll
    for (int w = 0; w < NTW; w++)
#pragma unroll
      for (int r = 0; r < 4; r++) {
        int row = mt * 16 + quad * 4 + r;
        int col = w * 16 + l16;
        Acc[(wave * 32 + row) * 50 + col] = acc[mt][w][r];
      }
  __syncthreads();

  // epilogue over 32 x (16*NTW) tile
  const int CW = 16 * NTW;
  for (int idx = tid; idx < 32 * CW; idx += 256) {
    int r = idx / CW, c = idx % CW;
    int j = n0 + c;
    if (j >= NN) continue;
    float v1 = Acc[(0 * 32 + r) * 50 + c] + bias4[0][j];
    float v2 = Acc[(1 * 32 + r) * 50 + c] + bias4[1][j];
    float va = Acc[(2 * 32 + r) * 50 + c] + bias4[2][j];
    float vb = Acc[(3 * 32 + r) * 50 + c] + bias4[3][j];
    float ff1 = tanhf(v1);
    float ff2 = tanhf(v2);
    float s = 1.f / (1.f + expf(-(va + vb)));
    float h = ff1 * (1.f - s) + s * ff2;
    size_t b = (size_t)(b0 + r);
    coh_store(hout + b * 1024 + j, h);        // cross-block state: bypass caches
    if (out2) out2[b * 16384 + j] = h;        // pred: consumed next dispatch
  }
}

struct PParams {
  const float* x;
  float* h0; float* h1;
  const ushort* wf0[4]; const ushort* wf1[4]; const ushort* wf2[4];
  int loOff0, loOff1, loOff2;
  const float* bias0[4]; const float* bias1[4]; const float* bias2[4];
  float* pred;
  int* bar;
};

// Chain barrier (fan-in `target`): drain own coherent stores, one RELAXED
// system-scope add + spin. Monotonic slots (memset once) -> no ABA, no reset.
__device__ __forceinline__ void chain_barrier(int* slot, int target) {
  asm volatile("s_waitcnt vmcnt(0)" ::: "memory");
  __syncthreads();
  if (threadIdx.x == 0) {
    __hip_atomic_fetch_add(slot, 1, __ATOMIC_RELAXED, __HIP_MEMORY_SCOPE_SYSTEM);
    while (__hip_atomic_load(slot, __ATOMIC_RELAXED, __HIP_MEMORY_SCOPE_SYSTEM) < target)
      __builtin_amdgcn_s_sleep(1);
  }
  __syncthreads();
}

// ---------------------------------------------------------------------------
// Persistent kernel: 16 independent row-chains (32 batch rows each) x 12
// blocks (feature columns). Rows never mix across chains, so barriers are
// per-chain: fan-in 12 after L0/L1, fan-in 4 after L2 (only ntp<4 touch h2).
// 192 blocks <= 256 CUs at 1 block/CU -> co-residency safe. blk = c*12+ntp
// puts each weight slice on 2 XCDs (blk%8 pattern) -> better L2 residency.
// ---------------------------------------------------------------------------
__global__ __launch_bounds__(256, 1) void cfc_persistent(PParams p) {
  __shared__ ushort Ah[2 * 32 * 40];
  __shared__ ushort Al[2 * 32 * 40];
  __shared__ float  Acc[4 * 32 * 50];
  const int blk = blockIdx.x;
  const int c = blk / CBLK, ntp = blk % CBLK;
  const int b0 = c * 32;
  int* cbar = p.bar + c * (T * 3);

  for (int t = 0; t < T; t++) {
    float* hr = (t & 1) ? p.h1 : p.h0;
    float* hw = (t & 1) ? p.h0 : p.h1;
    // layer 0: xc = [x_t(512) cached, h0_old(538) coherent]
    cell_job<3, false, true, 33>(Ah, Al, Acc, p.x + (size_t)t * 512, T * 512, hr, 1024,
                                 512, 1050, 36, p.loOff0, p.wf0, p.bias0, 538,
                                 hw, nullptr, b0, ntp);
    chain_barrier(cbar + t * 3, CBLK);
    // layer 1: xc = [h0_new(538), h1_old(358)]
    cell_job<2, true, true, 28>(Ah, Al, Acc, hw, 1024, hr + 538, 1024,
                                538, 896, 24, p.loOff1, p.wf1, p.bias1, 358,
                                hw + 538, nullptr, b0, ntp);
    chain_barrier(cbar + t * 3 + 1, CBLK);
    // layer 2: xc = [h1_new(358), h2_old(128)]; writes pred[:, t, :]
    if (ntp < 4) {
      cell_job<2, true, true, 16>(Ah, Al, Acc, hw + 538, 1024, hr + 896, 1024,
                                  358, 486, 8, p.loOff2, p.wf2, p.bias2, 128,
                                  hw + 896, p.pred + (size_t)t * 128, b0, ntp);
      chain_barrier(cbar + t * 3 + 2, 4);
    }
  }
}

// ---------------------------------------------------------------------------
// Final linear, IN PLACE on io (f32 d_out predictions region).
// ---------------------------------------------------------------------------
__global__ __launch_bounds__(256)
void final_linear(float* __restrict__ io, const ushort* __restrict__ wfc_frag,
                  int loOff, const float* __restrict__ bfc) {
  __shared__ ushort Ah[64][136];
  __shared__ ushort Al[64][136];
  const int tid = threadIdx.x;
  const int wave = tid >> 6, lane = tid & 63, quad = lane >> 4, l16 = lane & 15;
  const size_t r0 = (size_t)blockIdx.x * 64;
  {
    const int row = tid >> 2;
    const int cb  = (tid & 3) * 32;
    const float* src = io + (r0 + row) * 128 + cb;
#pragma unroll
    for (int e = 0; e < 32; e++) {
      float v = src[e];
      ushort hi = f2bf(v);
      Ah[row][cb + e] = hi;
      Al[row][cb + e] = f2bf(v - bf2f(hi));
    }
  }
  __syncthreads();
  float4v acc[8];
#pragma unroll
  for (int i = 0; i < 8; i++) acc[i] = float4v{0.f, 0.f, 0.f, 0.f};
#pragma unroll
  for (int kb = 0; kb < 4; kb++) {
    short8 ah = *(const short8*)&Ah[wave * 16 + l16][kb * 32 + quad * 8];
    short8 al = *(const short8*)&Al[wave * 16 + l16][kb * 32 + quad * 8];
#pragma unroll
    for (int nt = 0; nt < 8; nt++) {
      const size_t fo = ((size_t)(kb * 8 + nt) * 64 + lane) * 8;
      short8 bh = *(const short8*)(wfc_frag + fo);
      short8 bl = *(const short8*)(wfc_frag + loOff + fo);
      acc[nt] = __builtin_amdgcn_mfma_f32_16x16x32_bf16(ah, bh, acc[nt], 0, 0, 0);
      acc[nt] = __builtin_amdgcn_mfma_f32_16x16x32_bf16(al, bh, acc[nt], 0, 0, 0);
      acc[nt] = __builtin_amdgcn_mfma_f32_16x16x32_bf16(ah, bl, acc[nt], 0, 0, 0);
    }
  }
  __syncthreads();
#pragma unroll
  for (int nt = 0; nt < 8; nt++) {
    int col = nt * 16 + l16;
    float bb = bfc[col];
#pragma unroll
    for (int r = 0; r < 4; r++) {
      int row = wave * 16 + quad * 4 + r;
      io[(r0 + row) * 128 + col] = acc[nt][r] + bb;
    }
  }
}

// ---------------------------------------------------------------------------
extern "C" void kernel_launch(void* const* d_in, const int* in_sizes, int n_in,
                              void* d_out, int out_size, void* d_ws, size_t ws_size,
                              hipStream_t stream) {
  const int maskIdx[3] = {2, 11, 20};
  const int wIdx[3]    = {3, 12, 21};
  const float* Wfc = (const float*)d_in[29];
  const float* bfc = (const float*)d_in[30];

  const int KBs[3] = {33, 28, 16};
  const int NTs[3] = {36, 24, 8};   // L0 padded 34->36 for 12-block jobs
  const int NNs[3] = {538, 358, 128};
  const int ITs[3] = {1050, 896, 486};

  ushort* ws = (ushort*)d_ws;
  size_t off = 0;
  ushort* wf[3][4];
  int loOff[3];
  for (int l = 0; l < 3; l++) {
    loOff[l] = KBs[l] * NTs[l] * 512;
    for (int q = 0; q < 4; q++) {
      wf[l][q] = ws + off;
      off += (size_t)2 * loOff[l];
    }
  }
  int wfcLo = 4 * 8 * 512;
  ushort* wfc_f = ws + off; off += (size_t)2 * wfcLo;
  float* hb0 = (float*)(ws + off); off += (size_t)NB * 1024 * 2;
  float* hb1 = (float*)(ws + off); off += (size_t)NB * 1024 * 2;
  int* bar = (int*)(ws + off); off += (size_t)NCH * T * 3 * 2;

  float* pred = (float*)d_out;
  float* hn   = (float*)d_out + (size_t)NB * T * 128;

  for (int l = 0; l < 3; l++) {
    int blocks = (loOff[l] + 255) / 256;
    for (int q = 0; q < 4; q++) {
      const float* m = (q < 2) ? (const float*)d_in[maskIdx[l]] : nullptr;
      pack_w<<<blocks, 256, 0, stream>>>((const float*)d_in[wIdx[l] + q], m, wf[l][q],
                                         loOff[l], NNs[l], ITs[l], NTs[l], KBs[l]);
    }
  }
  pack_w<<<(wfcLo + 255) / 256, 256, 0, stream>>>(Wfc, nullptr, wfc_f, wfcLo, 128, 128, 8, 4);

  hipMemsetAsync(bar, 0, NCH * T * 3 * sizeof(int), stream);
  hipMemcpyAsync(hb0, d_in[1], (size_t)NB * 1024 * sizeof(float),
                 hipMemcpyDeviceToDevice, stream);

  PParams p;
  p.x = (const float*)d_in[0];
  p.h0 = hb0; p.h1 = hb1;
  for (int q = 0; q < 4; q++) {
    p.wf0[q] = wf[0][q]; p.wf1[q] = wf[1][q]; p.wf2[q] = wf[2][q];
    p.bias0[q] = (const float*)d_in[7 + q];
    p.bias1[q] = (const float*)d_in[16 + q];
    p.bias2[q] = (const float*)d_in[25 + q];
  }
  p.loOff0 = loOff[0]; p.loOff1 = loOff[1]; p.loOff2 = loOff[2];
  p.pred = pred;
  p.bar = bar;

  cfc_persistent<<<NCH * CBLK, 256, 0, stream>>>(p);

  final_linear<<<(NB * T) / 64, 256, 0, stream>>>(pred, wfc_f, wfcLo, bfc);
  hipMemcpyAsync(hn, hb0, (size_t)NB * 1024 * sizeof(float),
                 hipMemcpyDeviceToDevice, stream);
}

// Round 3
// 5866.618 us; speedup vs baseline: 1.8194x; 1.1310x over previous
//
#include <hip/hip_runtime.h>
#include <stdint.h>

typedef __attribute__((ext_vector_type(8))) short short8;
typedef __attribute__((ext_vector_type(4))) float float4v;
typedef __attribute__((ext_vector_type(4))) unsigned short ushort4v;

constexpr int T = 128;
constexpr int NB = 512;          // batch
constexpr int NCH = 16;          // row chains (32 rows each)
constexpr int CBLK = 12;         // blocks per chain (feature-column parallelism)
// Padded hidden layout per row: h0 @0 (538->544), h1 @544 (358->384), h2 @928 (128)
constexpr int HS = 1056;

__device__ __forceinline__ float bf2f(ushort u) {
  union { float f; uint32_t i; } v; v.i = ((uint32_t)u) << 16; return v.f;
}
__device__ __forceinline__ ushort f2bf(float f) {
  union { float f; uint32_t i; } v; v.f = f;
  uint32_t i = v.i;
  uint32_t r = i + 0x7FFFu + ((i >> 16) & 1u);
  return (ushort)(r >> 16);
}

// Coherent (sc0 sc1 cache-bypassing) 8B accessors for cross-block h state.
// RELAXED+SYSTEM => plain global_load/store_dwordx2 sc0 sc1, no fences.
__device__ __forceinline__ unsigned long long coh_load8(const float* p) {
  return __hip_atomic_load(
      reinterpret_cast<unsigned long long*>(const_cast<float*>(p)),
      __ATOMIC_RELAXED, __HIP_MEMORY_SCOPE_SYSTEM);
}
__device__ __forceinline__ void coh_store8(float* p, float a, float b) {
  union { unsigned long long u; float f[2]; } v; v.f[0] = a; v.f[1] = b;
  __hip_atomic_store(reinterpret_cast<unsigned long long*>(p), v.u,
                     __ATOMIC_RELAXED, __HIP_MEMORY_SCOPE_SYSTEM);
}

// ---------------------------------------------------------------------------
// Pack f32 weights (optionally masked) into SPLIT bf16 MFMA B-fragment layout,
// with k-axis SEGMENT ROTATION: packed k index p maps to source column
//   p <  POLD : src = SOFF + p   (valid if p < OLDLEN, else zero)   [old-state]
//   p >= POLD : src = p - POLD   (valid if src < NEWLEN, else zero) [new-state]
// ---------------------------------------------------------------------------
__global__ __launch_bounds__(256) void pack_w(const float* __restrict__ W,
                                              const float* __restrict__ mask,
                                              ushort* __restrict__ out, int loOff,
                                              int NN, int IT, int NT, int KB,
                                              int POLD, int OLDLEN, int SOFF,
                                              int NEWLEN) {
  int idx = blockIdx.x * 256 + threadIdx.x;
  int total = KB * NT * 512;
  if (idx >= total) return;
  int jj   = idx & 7;
  int lane = (idx >> 3) & 63;
  int nt   = (idx >> 9) % NT;
  int kb   = (idx >> 9) / NT;
  int n = nt * 16 + (lane & 15);
  int p = kb * 32 + (lane >> 4) * 8 + jj;
  int src = -1;
  if (p < POLD) {
    if (p < OLDLEN) src = SOFF + p;
  } else {
    int q = p - POLD;
    if (q < NEWLEN) src = q;
  }
  float v = 0.f;
  if (n < NN && src >= 0) {
    v = W[(size_t)n * IT + src];
    if (mask) v *= mask[(size_t)n * IT + src];
  }
  ushort hi = f2bf(v);
  out[idx] = hi;
  out[loOff + idx] = f2bf(v - bf2f(hi));
}

// ---------------------------------------------------------------------------
// One k-range of a cell tile: kb in [KB0,KB1), A data from ONE contiguous
// segment (aRow + (kb-KOFF)*32), depth-4 pipeline, raw s_barrier (no vmcnt
// drain) so prefetches stay in flight across barriers. Accumulates into acc.
// Segment padding guarantees every 4-float A read is in-bounds (pads are 0).
// ---------------------------------------------------------------------------
template <int NTW, bool COH, int KB0, int KB1, int KOFF>
__device__ __forceinline__ void cell_range(
    ushort* __restrict__ Ah, ushort* __restrict__ Al,
    const float* __restrict__ aRow,      // this thread's staging-row base
    const ushort* __restrict__ wfq, int nt0, int NT, int loOff,
    float4v (&acc)[2][NTW]) {
  constexpr int PD = 4;                  // pipeline depth; all ranges have >=4 kb
  constexpr int LEN = KB1 - KB0;
  const int tid  = threadIdx.x;
  const int lane = tid & 63, quad = lane >> 4, l16 = lane & 15;
  const int sm = tid >> 3;               // staging row 0..31
  const int sk = (tid & 7) * 4;          // staging col base

  short8 cbh[PD][NTW], cbl[PD][NTW];
  float4v av[PD];

  auto loadB = [&](int kb, short8* bh, short8* bl) {
#pragma unroll
    for (int w = 0; w < NTW; w++) {
      const size_t fo = ((size_t)(kb * NT + nt0 + w) * 64 + lane) * 8;
      bh[w] = *(const short8*)(wfq + fo);
      bl[w] = *(const short8*)(wfq + loOff + fo);
    }
  };
  auto loadA = [&](int kb) -> float4v {
    const float* p = aRow + (kb - KOFF) * 32 + sk;
    float4v r;
    if (COH) {
      union { unsigned long long u; float f[2]; } x0, x1;
      x0.u = coh_load8(p);
      x1.u = coh_load8(p + 2);
      r[0] = x0.f[0]; r[1] = x0.f[1]; r[2] = x1.f[0]; r[3] = x1.f[1];
    } else {
      r = *(const float4v*)p;
    }
    return r;
  };

#pragma unroll
  for (int i = 0; i < PD; i++) { av[i] = loadA(KB0 + i); loadB(KB0 + i, cbh[i], cbl[i]); }

  for (int kb0 = KB0; kb0 < KB1; kb0 += PD) {
#pragma unroll
    for (int u = 0; u < PD; u++) {
      const int kb = kb0 + u;
      if ((LEN % PD) && kb >= KB1) continue;   // folds away when LEN%PD==0
      const int ab = (kb & 1) * 1280;          // LDS A double buffer (parity-keyed)

      ushort4v hi4, lo4;
#pragma unroll
      for (int e = 0; e < 4; e++) {
        float v = av[u][e];
        ushort hi = f2bf(v);
        hi4[e] = hi;
        lo4[e] = f2bf(v - bf2f(hi));
      }
      *(ushort4v*)(Ah + ab + sm * 40 + sk) = hi4;
      *(ushort4v*)(Al + ab + sm * 40 + sk) = lo4;
      // LDS writes visible, then barrier. NO vmcnt drain: outstanding
      // prefetches for later slots stay in flight across the barrier.
      asm volatile("s_waitcnt lgkmcnt(0)\n\ts_barrier" ::: "memory");

#pragma unroll
      for (int mt = 0; mt < 2; mt++) {
        short8 ah = *(const short8*)&Ah[ab + (mt * 16 + l16) * 40 + quad * 8];
        short8 al = *(const short8*)&Al[ab + (mt * 16 + l16) * 40 + quad * 8];
#pragma unroll
        for (int w = 0; w < NTW; w++) {
          acc[mt][w] = __builtin_amdgcn_mfma_f32_16x16x32_bf16(ah, cbh[u][w], acc[mt][w], 0, 0, 0);
          acc[mt][w] = __builtin_amdgcn_mfma_f32_16x16x32_bf16(al, cbh[u][w], acc[mt][w], 0, 0, 0);
          acc[mt][w] = __builtin_amdgcn_mfma_f32_16x16x32_bf16(ah, cbl[u][w], acc[mt][w], 0, 0, 0);
        }
      }
      if (kb + PD < KB1) { av[u] = loadA(kb + PD); loadB(kb + PD, cbh[u], cbl[u]); }
    }
  }
}

// ---------------------------------------------------------------------------
// Cross-wave combine + CfC nonlinearity + coherent h store (8B vectors).
// Pads [NN, NNPAD) are written as ZERO to keep the padded-h zero invariant.
// ---------------------------------------------------------------------------
template <int NTW>
__device__ __forceinline__ void cell_epilogue(
    float* __restrict__ Acc, float4v (&acc)[2][NTW],
    const float* const* __restrict__ bias4,
    int NN, int NNPAD, float* __restrict__ hout, float* __restrict__ out2,
    int b0, int n0) {
  const int tid = threadIdx.x;
  const int wave = tid >> 6, lane = tid & 63, quad = lane >> 4, l16 = lane & 15;
#pragma unroll
  for (int mt = 0; mt < 2; mt++)
#pragma unroll
    for (int w = 0; w < NTW; w++)
#pragma unroll
      for (int r = 0; r < 4; r++)
        Acc[(wave * 32 + mt * 16 + quad * 4 + r) * 50 + w * 16 + l16] = acc[mt][w][r];
  __syncthreads();
  constexpr int CW = 16 * NTW;
  for (int i4 = tid; i4 < 32 * (CW / 4); i4 += 256) {
    const int r = i4 / (CW / 4);
    const int c4 = (i4 % (CW / 4)) * 4;
    const int j0 = n0 + c4;
    if (j0 >= NNPAD) continue;
    float hv[4];
#pragma unroll
    for (int e = 0; e < 4; e++) {
      const int c = c4 + e, j = j0 + e;
      float h = 0.f;
      if (j < NN) {
        float v1 = Acc[(0 * 32 + r) * 50 + c] + bias4[0][j];
        float v2 = Acc[(1 * 32 + r) * 50 + c] + bias4[1][j];
        float va = Acc[(2 * 32 + r) * 50 + c] + bias4[2][j];
        float vb = Acc[(3 * 32 + r) * 50 + c] + bias4[3][j];
        float ff1 = tanhf(v1);
        float ff2 = tanhf(v2);
        float s = 1.f / (1.f + expf(-(va + vb)));
        h = ff1 * (1.f - s) + s * ff2;
      }
      hv[e] = h;
    }
    float* hp = hout + (size_t)(b0 + r) * HS + j0;
    coh_store8(hp, hv[0], hv[1]);
    coh_store8(hp + 2, hv[2], hv[3]);
    if (out2) {
      float4v o; o[0] = hv[0]; o[1] = hv[1]; o[2] = hv[2]; o[3] = hv[3];
      *(float4v*)(out2 + (size_t)(b0 + r) * 16384 + j0) = o;
    }
  }
}

struct PParams {
  const float* x;
  float* h0; float* h1;
  const ushort* wf0[4]; const ushort* wf1[4]; const ushort* wf2[4];
  int loOff0, loOff1, loOff2;
  const float* bias0[4]; const float* bias1[4]; const float* bias2[4];
  float* pred;
  int* bar;
};

// Split barrier. Arrive: per-wave vmcnt drain (coherent stores acked at the
// coherence point) -> block barrier -> one RELAXED system add. Wait: thread0
// spins on the monotonic slot, then block barrier releases everyone.
__device__ __forceinline__ void bar_arrive(int* slot) {
  asm volatile("s_waitcnt vmcnt(0)" ::: "memory");
  __syncthreads();
  if (threadIdx.x == 0)
    __hip_atomic_fetch_add(slot, 1, __ATOMIC_RELAXED, __HIP_MEMORY_SCOPE_SYSTEM);
}
__device__ __forceinline__ void bar_wait(int* slot, int target) {
  if (threadIdx.x == 0) {
    while (__hip_atomic_load(slot, __ATOMIC_RELAXED, __HIP_MEMORY_SCOPE_SYSTEM) < target)
      __builtin_amdgcn_s_sleep(1);
  }
  __syncthreads();
}

// ---------------------------------------------------------------------------
// Persistent kernel: 16 chains x 12 blocks. k-axes are rotated so each
// phase consumes the already-synchronized state segment FIRST; the wait on
// the fresh barrier is taken mid-k-loop, hidden behind MFMA work.
//   L0: [x(512) | h0_old]           -> no wait inside (inputs all old)
//   L1: [h1_old(358p384) | h0_new]  -> wait(t,0) after 12 k-blocks
//   L2: [h2_old(128) | h1_new]      -> wait(t,1) after 4 k-blocks
// ---------------------------------------------------------------------------
__global__ __launch_bounds__(256, 1) void cfc_persistent(PParams p) {
  __shared__ ushort Ah[2 * 32 * 40];
  __shared__ ushort Al[2 * 32 * 40];
  __shared__ float  Acc[4 * 32 * 50];
  const int blk = blockIdx.x;
  const int c = blk / CBLK, ntp = blk % CBLK;
  const int b0 = c * 32;
  int* cbar = p.bar + c * (T * 3);
  const int wave = threadIdx.x >> 6;
  const int sm = threadIdx.x >> 3;
  const size_t rowoff = (size_t)(b0 + sm);

  for (int t = 0; t < T; t++) {
    float* hr = (t & 1) ? p.h1 : p.h0;
    float* hw = (t & 1) ? p.h0 : p.h1;
    const float* xRow  = p.x + rowoff * (T * 512) + (size_t)t * 512;
    const float* hrRow = hr + rowoff * HS;
    const float* hwRow = hw + rowoff * HS;

    // ---- layer 0: inputs all pre-synchronized ----
    float4v acc0[2][3];
#pragma unroll
    for (int i = 0; i < 2; i++)
#pragma unroll
      for (int w = 0; w < 3; w++) acc0[i][w] = float4v{0.f, 0.f, 0.f, 0.f};
    cell_range<3, false, 0, 16, 0 >(Ah, Al, xRow,  p.wf0[wave], ntp * 3, 36, p.loOff0, acc0);
    cell_range<3, true, 16, 33, 16>(Ah, Al, hrRow, p.wf0[wave], ntp * 3, 36, p.loOff0, acc0);
    cell_epilogue<3>(Acc, acc0, p.bias0, 538, 544, hw, nullptr, b0, ntp * 48);
    bar_arrive(cbar + t * 3);

    // ---- layer 1 ----
    if (t && ntp >= 4) bar_wait(cbar + (t - 1) * 3 + 1, CBLK);  // h1_old ready
    float4v acc1[2][2];
#pragma unroll
    for (int i = 0; i < 2; i++)
#pragma unroll
      for (int w = 0; w < 2; w++) acc1[i][w] = float4v{0.f, 0.f, 0.f, 0.f};
    cell_range<2, true, 0, 12, 0 >(Ah, Al, hrRow + 544, p.wf1[wave], ntp * 2, 24, p.loOff1, acc1);
    bar_wait(cbar + t * 3, CBLK);                               // h0_new ready
    cell_range<2, true, 12, 29, 12>(Ah, Al, hwRow, p.wf1[wave], ntp * 2, 24, p.loOff1, acc1);
    cell_epilogue<2>(Acc, acc1, p.bias1, 358, 384, hw + 544, nullptr, b0, ntp * 32);
    bar_arrive(cbar + t * 3 + 1);

    // ---- layer 2 (4 blocks per chain) ----
    if (ntp < 4) {
      if (t) bar_wait(cbar + (t - 1) * 3 + 2, 4);               // h2_old ready
      float4v acc2[2][2];
#pragma unroll
      for (int i = 0; i < 2; i++)
#pragma unroll
        for (int w = 0; w < 2; w++) acc2[i][w] = float4v{0.f, 0.f, 0.f, 0.f};
      cell_range<2, true, 0, 4, 0>(Ah, Al, hrRow + 928, p.wf2[wave], ntp * 2, 8, p.loOff2, acc2);
      bar_wait(cbar + t * 3 + 1, CBLK);                         // h1_new ready
      cell_range<2, true, 4, 16, 4>(Ah, Al, hwRow + 544, p.wf2[wave], ntp * 2, 8, p.loOff2, acc2);
      cell_epilogue<2>(Acc, acc2, p.bias2, 128, 128, hw + 928,
                       p.pred + (size_t)t * 128, b0, ntp * 32);
      bar_arrive(cbar + t * 3 + 2);
    }
  }
}

// ---------------------------------------------------------------------------
// h layout helpers: scatter packed(1024) -> padded(HS) with zeroed pads,
// gather padded -> packed for the hn output.
// ---------------------------------------------------------------------------
__global__ __launch_bounds__(256) void h_scatter(const float* __restrict__ src,
                                                 float* __restrict__ dst) {
  int idx = blockIdx.x * 256 + threadIdx.x;
  if (idx >= NB * HS) return;
  int b = idx / HS, u = idx % HS;
  int s = -1;
  if (u < 538) s = u;
  else if (u >= 544 && u < 902) s = 538 + (u - 544);
  else if (u >= 928) s = 896 + (u - 928);
  dst[idx] = (s >= 0) ? src[(size_t)b * 1024 + s] : 0.f;
}
__global__ __launch_bounds__(256) void h_gather(const float* __restrict__ src,
                                                float* __restrict__ dst) {
  int idx = blockIdx.x * 256 + threadIdx.x;
  if (idx >= NB * 1024) return;
  int b = idx / 1024, u = idx % 1024;
  int pu = (u < 538) ? u : (u < 896 ? (u - 538) + 544 : (u - 896) + 928);
  dst[idx] = src[(size_t)b * HS + pu];
}

// ---------------------------------------------------------------------------
// Final linear, IN PLACE on io (f32 d_out predictions region).
// ---------------------------------------------------------------------------
__global__ __launch_bounds__(256)
void final_linear(float* __restrict__ io, const ushort* __restrict__ wfc_frag,
                  int loOff, const float* __restrict__ bfc) {
  __shared__ ushort Ah[64][136];
  __shared__ ushort Al[64][136];
  const int tid = threadIdx.x;
  const int wave = tid >> 6, lane = tid & 63, quad = lane >> 4, l16 = lane & 15;
  const size_t r0 = (size_t)blockIdx.x * 64;
  {
    const int row = tid >> 2;
    const int cb  = (tid & 3) * 32;
    const float* src = io + (r0 + row) * 128 + cb;
#pragma unroll
    for (int e = 0; e < 32; e++) {
      float v = src[e];
      ushort hi = f2bf(v);
      Ah[row][cb + e] = hi;
      Al[row][cb + e] = f2bf(v - bf2f(hi));
    }
  }
  __syncthreads();
  float4v acc[8];
#pragma unroll
  for (int i = 0; i < 8; i++) acc[i] = float4v{0.f, 0.f, 0.f, 0.f};
#pragma unroll
  for (int kb = 0; kb < 4; kb++) {
    short8 ah = *(const short8*)&Ah[wave * 16 + l16][kb * 32 + quad * 8];
    short8 al = *(const short8*)&Al[wave * 16 + l16][kb * 32 + quad * 8];
#pragma unroll
    for (int nt = 0; nt < 8; nt++) {
      const size_t fo = ((size_t)(kb * 8 + nt) * 64 + lane) * 8;
      short8 bh = *(const short8*)(wfc_frag + fo);
      short8 bl = *(const short8*)(wfc_frag + loOff + fo);
      acc[nt] = __builtin_amdgcn_mfma_f32_16x16x32_bf16(ah, bh, acc[nt], 0, 0, 0);
      acc[nt] = __builtin_amdgcn_mfma_f32_16x16x32_bf16(al, bh, acc[nt], 0, 0, 0);
      acc[nt] = __builtin_amdgcn_mfma_f32_16x16x32_bf16(ah, bl, acc[nt], 0, 0, 0);
    }
  }
  __syncthreads();
#pragma unroll
  for (int nt = 0; nt < 8; nt++) {
    int col = nt * 16 + l16;
    float bb = bfc[col];
#pragma unroll
    for (int r = 0; r < 4; r++) {
      int row = wave * 16 + quad * 4 + r;
      io[(r0 + row) * 128 + col] = acc[nt][r] + bb;
    }
  }
}

// ---------------------------------------------------------------------------
extern "C" void kernel_launch(void* const* d_in, const int* in_sizes, int n_in,
                              void* d_out, int out_size, void* d_ws, size_t ws_size,
                              hipStream_t stream) {
  const int maskIdx[3] = {2, 11, 20};
  const int wIdx[3]    = {3, 12, 21};
  const float* Wfc = (const float*)d_in[29];
  const float* bfc = (const float*)d_in[30];

  const int KBs[3]  = {33, 29, 16};   // L1: 384(old,padded) + 538(new) = 922 -> 29 kb
  const int NTs[3]  = {36, 24, 8};    // L0 padded 34->36 for 12-block jobs
  const int NNs[3]  = {538, 358, 128};
  const int ITs[3]  = {1050, 896, 486};
  const int POLDs[3]   = {0, 384, 128};
  const int OLDLENs[3] = {0, 358, 128};
  const int SOFFs[3]   = {0, 538, 358};
  const int NEWLENs[3] = {1050, 538, 358};

  ushort* ws = (ushort*)d_ws;
  size_t off = 0;
  ushort* wf[3][4];
  int loOff[3];
  for (int l = 0; l < 3; l++) {
    loOff[l] = KBs[l] * NTs[l] * 512;
    for (int q = 0; q < 4; q++) {
      wf[l][q] = ws + off;
      off += (size_t)2 * loOff[l];
    }
  }
  int wfcLo = 4 * 8 * 512;
  ushort* wfc_f = ws + off; off += (size_t)2 * wfcLo;
  float* hb0 = (float*)(ws + off); off += (size_t)NB * HS * 2;
  float* hb1 = (float*)(ws + off); off += (size_t)NB * HS * 2;
  int* bar = (int*)(ws + off); off += (size_t)NCH * T * 3 * 2;

  float* pred = (float*)d_out;
  float* hn   = (float*)d_out + (size_t)NB * T * 128;

  for (int l = 0; l < 3; l++) {
    int blocks = (loOff[l] + 255) / 256;
    for (int q = 0; q < 4; q++) {
      const float* m = (q < 2) ? (const float*)d_in[maskIdx[l]] : nullptr;
      pack_w<<<blocks, 256, 0, stream>>>((const float*)d_in[wIdx[l] + q], m, wf[l][q],
                                         loOff[l], NNs[l], ITs[l], NTs[l], KBs[l],
                                         POLDs[l], OLDLENs[l], SOFFs[l], NEWLENs[l]);
    }
  }
  pack_w<<<(wfcLo + 255) / 256, 256, 0, stream>>>(Wfc, nullptr, wfc_f, wfcLo,
                                                  128, 128, 8, 4, 0, 0, 0, 128);

  hipMemsetAsync(bar, 0, NCH * T * 3 * sizeof(int), stream);
  h_scatter<<<(NB * HS + 255) / 256, 256, 0, stream>>>((const float*)d_in[1], hb0);

  PParams p;
  p.x = (const float*)d_in[0];
  p.h0 = hb0; p.h1 = hb1;
  for (int q = 0; q < 4; q++) {
    p.wf0[q] = wf[0][q]; p.wf1[q] = wf[1][q]; p.wf2[q] = wf[2][q];
    p.bias0[q] = (const float*)d_in[7 + q];
    p.bias1[q] = (const float*)d_in[16 + q];
    p.bias2[q] = (const float*)d_in[25 + q];
  }
  p.loOff0 = loOff[0]; p.loOff1 = loOff[1]; p.loOff2 = loOff[2];
  p.pred = pred;
  p.bar = bar;

  cfc_persistent<<<NCH * CBLK, 256, 0, stream>>>(p);

  final_linear<<<(NB * T) / 64, 256, 0, stream>>>(pred, wfc_f, wfcLo, bfc);
  h_gather<<<(NB * 1024 + 255) / 256, 256, 0, stream>>>(hb0, hn);
}

// Round 4
// 5749.052 us; speedup vs baseline: 1.8566x; 1.0204x over previous
//
#include <hip/hip_runtime.h>
#include <stdint.h>

typedef __attribute__((ext_vector_type(8))) short short8;
typedef __attribute__((ext_vector_type(4))) float float4v;
typedef __attribute__((ext_vector_type(4))) unsigned short ushort4v;

constexpr int T = 128;
constexpr int NB = 512;          // batch
constexpr int NCH = 16;          // row chains (32 rows each)
constexpr int CBLK = 12;         // blocks per chain (feature-column parallelism)
// Padded hidden layout per row: h0 @0 (538->544), h1 @544 (358->384), h2 @928 (128)
constexpr int HS = 1056;

__device__ __forceinline__ float bf2f(ushort u) {
  union { float f; uint32_t i; } v; v.i = ((uint32_t)u) << 16; return v.f;
}
__device__ __forceinline__ ushort f2bf(float f) {
  union { float f; uint32_t i; } v; v.f = f;
  uint32_t i = v.i;
  uint32_t r = i + 0x7FFFu + ((i >> 16) & 1u);
  return (ushort)(r >> 16);
}

// Cross-block h state: AGENT scope (device coherence point = MALL, which can
// CACHE these, unlike the system-scope path). RELAXED -> plain loads/stores
// with the right sc flags, no fences.
__device__ __forceinline__ unsigned long long coh_load8(const float* p) {
  return __hip_atomic_load(
      reinterpret_cast<unsigned long long*>(const_cast<float*>(p)),
      __ATOMIC_RELAXED, __HIP_MEMORY_SCOPE_AGENT);
}
__device__ __forceinline__ void coh_store8(float* p, float a, float b) {
  union { unsigned long long u; float f[2]; } v; v.f[0] = a; v.f[1] = b;
  __hip_atomic_store(reinterpret_cast<unsigned long long*>(p), v.u,
                     __ATOMIC_RELAXED, __HIP_MEMORY_SCOPE_AGENT);
}

// ---------------------------------------------------------------------------
// Pack f32 weights (optionally masked) into SPLIT bf16 MFMA B-fragment layout,
// with k-axis SEGMENT ROTATION: packed k index p maps to source column
//   p <  POLD : src = SOFF + p   (valid if p < OLDLEN, else zero)   [old-state]
//   p >= POLD : src = p - POLD   (valid if src < NEWLEN, else zero) [new-state]
// ---------------------------------------------------------------------------
__global__ __launch_bounds__(256) void pack_w(const float* __restrict__ W,
                                              const float* __restrict__ mask,
                                              ushort* __restrict__ out, int loOff,
                                              int NN, int IT, int NT, int KB,
                                              int POLD, int OLDLEN, int SOFF,
                                              int NEWLEN) {
  int idx = blockIdx.x * 256 + threadIdx.x;
  int total = KB * NT * 512;
  if (idx >= total) return;
  int jj   = idx & 7;
  int lane = (idx >> 3) & 63;
  int nt   = (idx >> 9) % NT;
  int kb   = (idx >> 9) / NT;
  int n = nt * 16 + (lane & 15);
  int p = kb * 32 + (lane >> 4) * 8 + jj;
  int src = -1;
  if (p < POLD) {
    if (p < OLDLEN) src = SOFF + p;
  } else {
    int q = p - POLD;
    if (q < NEWLEN) src = q;
  }
  float v = 0.f;
  if (n < NN && src >= 0) {
    v = W[(size_t)n * IT + src];
    if (mask) v *= mask[(size_t)n * IT + src];
  }
  ushort hi = f2bf(v);
  out[idx] = hi;
  out[loOff + idx] = f2bf(v - bf2f(hi));
}

// ---------------------------------------------------------------------------
// One k-range of a cell tile: kb in [KB0,KB1), A data from ONE contiguous
// segment (aRow + (kb-KOFF)*32). Depth-4 register pipeline; k-steps processed
// in PAIRS with ONE raw s_barrier per pair (no vmcnt drain -> prefetches stay
// in flight across barriers). LDS A uses a 4-buffer rotation keyed by slot,
// giving >=2 barriers between a buffer's last read and its next overwrite.
// Segment padding guarantees every 4-float A read is in-bounds (pads are 0).
// ---------------------------------------------------------------------------
template <int NTW, bool COH, int KB0, int KB1, int KOFF>
__device__ __forceinline__ void cell_range(
    ushort* __restrict__ Ast,            // 4 bufs x {hi[1280], lo[1280]} ushorts
    const float* __restrict__ aRow,      // this thread's staging-row base
    const ushort* __restrict__ wfq, int nt0, int NT, int loOff,
    float4v (&acc)[2][NTW]) {
  constexpr int PD = 4;
  constexpr int LEN = KB1 - KB0;
  constexpr int LEN2 = LEN & ~1;
  static_assert(LEN2 % PD == 0, "even part of every segment must be x4");
  const int tid  = threadIdx.x;
  const int lane = tid & 63, quad = lane >> 4, l16 = lane & 15;
  const int sm = tid >> 3;               // staging row 0..31
  const int sk = (tid & 7) * 4;          // staging col base

  short8 cbh[PD][NTW], cbl[PD][NTW];
  float4v av[PD];

  auto loadB = [&](int kb, short8 (&bh)[NTW], short8 (&bl)[NTW]) {
#pragma unroll
    for (int w = 0; w < NTW; w++) {
      const size_t fo = ((size_t)(kb * NT + nt0 + w) * 64 + lane) * 8;
      bh[w] = *(const short8*)(wfq + fo);
      bl[w] = *(const short8*)(wfq + loOff + fo);
    }
  };
  auto loadA = [&](int kb) -> float4v {
    const float* p = aRow + (kb - KOFF) * 32 + sk;
    float4v r;
    if (COH) {
      union { unsigned long long u; float f[2]; } x0, x1;
      x0.u = coh_load8(p);
      x1.u = coh_load8(p + 2);
      r[0] = x0.f[0]; r[1] = x0.f[1]; r[2] = x1.f[0]; r[3] = x1.f[1];
    } else {
      r = *(const float4v*)p;
    }
    return r;
  };
  auto stageSlot = [&](int u, float4v a) {
    ushort4v hi4, lo4;
#pragma unroll
    for (int e = 0; e < 4; e++) {
      float v = a[e];
      ushort hi = f2bf(v);
      hi4[e] = hi;
      lo4[e] = f2bf(v - bf2f(hi));
    }
    *(ushort4v*)(Ast + u * 2560 + sm * 40 + sk) = hi4;
    *(ushort4v*)(Ast + u * 2560 + 1280 + sm * 40 + sk) = lo4;
  };
  auto mfmaSlot = [&](int u, const short8 (&bh)[NTW], const short8 (&bl)[NTW]) {
#pragma unroll
    for (int mt = 0; mt < 2; mt++) {
      short8 ah = *(const short8*)(Ast + u * 2560 + (mt * 16 + l16) * 40 + quad * 8);
      short8 al = *(const short8*)(Ast + u * 2560 + 1280 + (mt * 16 + l16) * 40 + quad * 8);
#pragma unroll
      for (int w = 0; w < NTW; w++) {
        acc[mt][w] = __builtin_amdgcn_mfma_f32_16x16x32_bf16(ah, bh[w], acc[mt][w], 0, 0, 0);
        acc[mt][w] = __builtin_amdgcn_mfma_f32_16x16x32_bf16(al, bh[w], acc[mt][w], 0, 0, 0);
        acc[mt][w] = __builtin_amdgcn_mfma_f32_16x16x32_bf16(ah, bl[w], acc[mt][w], 0, 0, 0);
      }
    }
  };

  // prologue: fill all PD slots (loads overlap; first consumed ~latency later)
#pragma unroll
  for (int i = 0; i < PD; i++) { av[i] = loadA(KB0 + i); loadB(KB0 + i, cbh[i], cbl[i]); }

  for (int kb0 = KB0; kb0 < KB0 + LEN2; kb0 += PD) {
#pragma unroll
    for (int up = 0; up < 2; up++) {
      const int u0 = up * 2, u1 = up * 2 + 1;
      const int kb = kb0 + up * 2;
      stageSlot(u0, av[u0]);
      stageSlot(u1, av[u1]);
      // LDS writes drained, then barrier. NO vmcnt drain: outstanding global
      // prefetches for later slots stay in flight across the barrier.
      asm volatile("s_waitcnt lgkmcnt(0)\n\ts_barrier" ::: "memory");
      mfmaSlot(u0, cbh[u0], cbl[u0]);
      mfmaSlot(u1, cbh[u1], cbl[u1]);
      if (kb + PD < KB1)     { av[u0] = loadA(kb + PD);     loadB(kb + PD,     cbh[u0], cbl[u0]); }
      if (kb + 1 + PD < KB1) { av[u1] = loadA(kb + 1 + PD); loadB(kb + 1 + PD, cbh[u1], cbl[u1]); }
    }
  }
  if (LEN & 1) {             // odd tail: slot 0 (LEN2 % 4 == 0)
    stageSlot(0, av[0]);
    asm volatile("s_waitcnt lgkmcnt(0)\n\ts_barrier" ::: "memory");
    mfmaSlot(0, cbh[0], cbl[0]);
  }
}

// ---------------------------------------------------------------------------
// Cross-wave combine + CfC nonlinearity + coherent h store (8B vectors).
// Pads [NN, NNPAD) are written as ZERO to keep the padded-h zero invariant.
// ---------------------------------------------------------------------------
template <int NTW>
__device__ __forceinline__ void cell_epilogue(
    float* __restrict__ Acc, float4v (&acc)[2][NTW],
    const float* const* __restrict__ bias4,
    int NN, int NNPAD, float* __restrict__ hout, float* __restrict__ out2,
    int b0, int n0) {
  const int tid = threadIdx.x;
  const int wave = tid >> 6, lane = tid & 63, quad = lane >> 4, l16 = lane & 15;
  __syncthreads();   // all waves done with LDS A buffers before Acc reuse窗口
#pragma unroll
  for (int mt = 0; mt < 2; mt++)
#pragma unroll
    for (int w = 0; w < NTW; w++)
#pragma unroll
      for (int r = 0; r < 4; r++)
        Acc[(wave * 32 + mt * 16 + quad * 4 + r) * 50 + w * 16 + l16] = acc[mt][w][r];
  __syncthreads();
  constexpr int CW = 16 * NTW;
  for (int i4 = tid; i4 < 32 * (CW / 4); i4 += 256) {
    const int r = i4 / (CW / 4);
    const int c4 = (i4 % (CW / 4)) * 4;
    const int j0 = n0 + c4;
    if (j0 >= NNPAD) continue;
    float hv[4];
#pragma unroll
    for (int e = 0; e < 4; e++) {
      const int c = c4 + e, j = j0 + e;
      float h = 0.f;
      if (j < NN) {
        float v1 = Acc[(0 * 32 + r) * 50 + c] + bias4[0][j];
        float v2 = Acc[(1 * 32 + r) * 50 + c] + bias4[1][j];
        float va = Acc[(2 * 32 + r) * 50 + c] + bias4[2][j];
        float vb = Acc[(3 * 32 + r) * 50 + c] + bias4[3][j];
        float ff1 = tanhf(v1);
        float ff2 = tanhf(v2);
        float s = 1.f / (1.f + expf(-(va + vb)));
        h = ff1 * (1.f - s) + s * ff2;
      }
      hv[e] = h;
    }
    float* hp = hout + (size_t)(b0 + r) * HS + j0;
    coh_store8(hp, hv[0], hv[1]);
    coh_store8(hp + 2, hv[2], hv[3]);
    if (out2) {
      float4v o; o[0] = hv[0]; o[1] = hv[1]; o[2] = hv[2]; o[3] = hv[3];
      *(float4v*)(out2 + (size_t)(b0 + r) * 16384 + j0) = o;
    }
  }
}

struct PParams {
  const float* x;
  float* h0; float* h1;
  const ushort* wf0[4]; const ushort* wf1[4]; const ushort* wf2[4];
  int loOff0, loOff1, loOff2;
  const float* bias0[4]; const float* bias1[4]; const float* bias2[4];
  float* pred;
  int* bar;
};

// Split barrier (AGENT scope: device coherence point, MALL-served).
// Arrive: drain own coherent stores (vmcnt ack) -> block barrier -> one add.
// Wait: thread0 spins on the monotonic slot, block barrier releases everyone.
__device__ __forceinline__ void bar_arrive(int* slot) {
  asm volatile("s_waitcnt vmcnt(0)" ::: "memory");
  __syncthreads();
  if (threadIdx.x == 0)
    __hip_atomic_fetch_add(slot, 1, __ATOMIC_RELAXED, __HIP_MEMORY_SCOPE_AGENT);
}
__device__ __forceinline__ void bar_wait(int* slot, int target) {
  if (threadIdx.x == 0) {
    while (__hip_atomic_load(slot, __ATOMIC_RELAXED, __HIP_MEMORY_SCOPE_AGENT) < target)
      __builtin_amdgcn_s_sleep(1);
  }
  __syncthreads();
}

// ---------------------------------------------------------------------------
// Persistent kernel: 16 chains x 12 blocks. Physical blockIdx is remapped so
// blocks sharing a weight slice (same ntp) land on the SAME XCD:
//   s = (phys%8)*24 + phys/8;  ntp = s/16;  c = s%16
// -> each XCD (phys%8) hosts s in [24x, 24x+24) = at most 2 ntp slices
//    (~3 MB packed weights) -> weight stream stays L2-resident.
// k-axes are rotated so each phase consumes the already-synchronized state
// segment FIRST; the wait on the fresh barrier is taken mid-k-loop.
// ---------------------------------------------------------------------------
__global__ __launch_bounds__(256, 1) void cfc_persistent(PParams p) {
  __shared__ ushort Ast[4 * 2560];        // 4 A bufs x {hi,lo} x 32x40
  __shared__ float  Acc[4 * 32 * 50];
  const int phys = blockIdx.x;
  const int s = (phys & 7) * 24 + (phys >> 3);
  const int ntp = s >> 4;                 // 0..11
  const int c   = s & 15;                 // 0..15
  const int b0 = c * 32;
  int* cbar = p.bar + c * (T * 3);
  const int wave = threadIdx.x >> 6;
  const int sm = threadIdx.x >> 3;
  const size_t rowoff = (size_t)(b0 + sm);

  for (int t = 0; t < T; t++) {
    float* hr = (t & 1) ? p.h1 : p.h0;
    float* hw = (t & 1) ? p.h0 : p.h1;
    const float* xRow  = p.x + rowoff * (T * 512) + (size_t)t * 512;
    const float* hrRow = hr + rowoff * HS;
    const float* hwRow = hw + rowoff * HS;

    // ---- layer 0: inputs all pre-synchronized ----
    float4v acc0[2][3];
#pragma unroll
    for (int i = 0; i < 2; i++)
#pragma unroll
      for (int w = 0; w < 3; w++) acc0[i][w] = float4v{0.f, 0.f, 0.f, 0.f};
    cell_range<3, false, 0, 16, 0 >(Ast, xRow,  p.wf0[wave], ntp * 3, 36, p.loOff0, acc0);
    cell_range<3, true, 16, 33, 16>(Ast, hrRow, p.wf0[wave], ntp * 3, 36, p.loOff0, acc0);
    cell_epilogue<3>(Acc, acc0, p.bias0, 538, 544, hw, nullptr, b0, ntp * 48);
    bar_arrive(cbar + t * 3);

    // ---- layer 1 ----
    if (t && ntp >= 4) bar_wait(cbar + (t - 1) * 3 + 1, CBLK);  // h1_old ready
    float4v acc1[2][2];
#pragma unroll
    for (int i = 0; i < 2; i++)
#pragma unroll
      for (int w = 0; w < 2; w++) acc1[i][w] = float4v{0.f, 0.f, 0.f, 0.f};
    cell_range<2, true, 0, 12, 0 >(Ast, hrRow + 544, p.wf1[wave], ntp * 2, 24, p.loOff1, acc1);
    bar_wait(cbar + t * 3, CBLK);                               // h0_new ready
    cell_range<2, true, 12, 29, 12>(Ast, hwRow, p.wf1[wave], ntp * 2, 24, p.loOff1, acc1);
    cell_epilogue<2>(Acc, acc1, p.bias1, 358, 384, hw + 544, nullptr, b0, ntp * 32);
    bar_arrive(cbar + t * 3 + 1);

    // ---- layer 2 (4 blocks per chain) ----
    if (ntp < 4) {
      if (t) bar_wait(cbar + (t - 1) * 3 + 2, 4);               // h2_old ready
      float4v acc2[2][2];
#pragma unroll
      for (int i = 0; i < 2; i++)
#pragma unroll
        for (int w = 0; w < 2; w++) acc2[i][w] = float4v{0.f, 0.f, 0.f, 0.f};
      cell_range<2, true, 0, 4, 0>(Ast, hrRow + 928, p.wf2[wave], ntp * 2, 8, p.loOff2, acc2);
      bar_wait(cbar + t * 3 + 1, CBLK);                         // h1_new ready
      cell_range<2, true, 4, 16, 4>(Ast, hwRow + 544, p.wf2[wave], ntp * 2, 8, p.loOff2, acc2);
      cell_epilogue<2>(Acc, acc2, p.bias2, 128, 128, hw + 928,
                       p.pred + (size_t)t * 128, b0, ntp * 32);
      bar_arrive(cbar + t * 3 + 2);
    }
  }
}

// ---------------------------------------------------------------------------
// h layout helpers: scatter packed(1024) -> padded(HS) with zeroed pads,
// gather padded -> packed for the hn output.
// ---------------------------------------------------------------------------
__global__ __launch_bounds__(256) void h_scatter(const float* __restrict__ src,
                                                 float* __restrict__ dst) {
  int idx = blockIdx.x * 256 + threadIdx.x;
  if (idx >= NB * HS) return;
  int b = idx / HS, u = idx % HS;
  int s = -1;
  if (u < 538) s = u;
  else if (u >= 544 && u < 902) s = 538 + (u - 544);
  else if (u >= 928) s = 896 + (u - 928);
  dst[idx] = (s >= 0) ? src[(size_t)b * 1024 + s] : 0.f;
}
__global__ __launch_bounds__(256) void h_gather(const float* __restrict__ src,
                                                float* __restrict__ dst) {
  int idx = blockIdx.x * 256 + threadIdx.x;
  if (idx >= NB * 1024) return;
  int b = idx / 1024, u = idx % 1024;
  int pu = (u < 538) ? u : (u < 896 ? (u - 538) + 544 : (u - 896) + 928);
  dst[idx] = src[(size_t)b * HS + pu];
}

// ---------------------------------------------------------------------------
// Final linear, IN PLACE on io (f32 d_out predictions region).
// ---------------------------------------------------------------------------
__global__ __launch_bounds__(256)
void final_linear(float* __restrict__ io, const ushort* __restrict__ wfc_frag,
                  int loOff, const float* __restrict__ bfc) {
  __shared__ ushort Ah[64][136];
  __shared__ ushort Al[64][136];
  const int tid = threadIdx.x;
  const int wave = tid >> 6, lane = tid & 63, quad = lane >> 4, l16 = lane & 15;
  const size_t r0 = (size_t)blockIdx.x * 64;
  {
    const int row = tid >> 2;
    const int cb  = (tid & 3) * 32;
    const float* src = io + (r0 + row) * 128 + cb;
#pragma unroll
    for (int e = 0; e < 32; e++) {
      float v = src[e];
      ushort hi = f2bf(v);
      Ah[row][cb + e] = hi;
      Al[row][cb + e] = f2bf(v - bf2f(hi));
    }
  }
  __syncthreads();
  float4v acc[8];
#pragma unroll
  for (int i = 0; i < 8; i++) acc[i] = float4v{0.f, 0.f, 0.f, 0.f};
#pragma unroll
  for (int kb = 0; kb < 4; kb++) {
    short8 ah = *(const short8*)&Ah[wave * 16 + l16][kb * 32 + quad * 8];
    short8 al = *(const short8*)&Al[wave * 16 + l16][kb * 32 + quad * 8];
#pragma unroll
    for (int nt = 0; nt < 8; nt++) {
      const size_t fo = ((size_t)(kb * 8 + nt) * 64 + lane) * 8;
      short8 bh = *(const short8*)(wfc_frag + fo);
      short8 bl = *(const short8*)(wfc_frag + loOff + fo);
      acc[nt] = __builtin_amdgcn_mfma_f32_16x16x32_bf16(ah, bh, acc[nt], 0, 0, 0);
      acc[nt] = __builtin_amdgcn_mfma_f32_16x16x32_bf16(al, bh, acc[nt], 0, 0, 0);
      acc[nt] = __builtin_amdgcn_mfma_f32_16x16x32_bf16(ah, bl, acc[nt], 0, 0, 0);
    }
  }
  __syncthreads();
#pragma unroll
  for (int nt = 0; nt < 8; nt++) {
    int col = nt * 16 + l16;
    float bb = bfc[col];
#pragma unroll
    for (int r = 0; r < 4; r++) {
      int row = wave * 16 + quad * 4 + r;
      io[(r0 + row) * 128 + col] = acc[nt][r] + bb;
    }
  }
}

// ---------------------------------------------------------------------------
extern "C" void kernel_launch(void* const* d_in, const int* in_sizes, int n_in,
                              void* d_out, int out_size, void* d_ws, size_t ws_size,
                              hipStream_t stream) {
  const int maskIdx[3] = {2, 11, 20};
  const int wIdx[3]    = {3, 12, 21};
  const float* Wfc = (const float*)d_in[29];
  const float* bfc = (const float*)d_in[30];

  const int KBs[3]  = {33, 29, 16};   // L1: 384(old,padded) + 538(new) = 922 -> 29 kb
  const int NTs[3]  = {36, 24, 8};    // L0 padded 34->36 for 12-block jobs
  const int NNs[3]  = {538, 358, 128};
  const int ITs[3]  = {1050, 896, 486};
  const int POLDs[3]   = {0, 384, 128};
  const int OLDLENs[3] = {0, 358, 128};
  const int SOFFs[3]   = {0, 538, 358};
  const int NEWLENs[3] = {1050, 538, 358};

  ushort* ws = (ushort*)d_ws;
  size_t off = 0;
  ushort* wf[3][4];
  int loOff[3];
  for (int l = 0; l < 3; l++) {
    loOff[l] = KBs[l] * NTs[l] * 512;
    for (int q = 0; q < 4; q++) {
      wf[l][q] = ws + off;
      off += (size_t)2 * loOff[l];
    }
  }
  int wfcLo = 4 * 8 * 512;
  ushort* wfc_f = ws + off; off += (size_t)2 * wfcLo;
  float* hb0 = (float*)(ws + off); off += (size_t)NB * HS * 2;
  float* hb1 = (float*)(ws + off); off += (size_t)NB * HS * 2;
  int* bar = (int*)(ws + off); off += (size_t)NCH * T * 3 * 2;

  float* pred = (float*)d_out;
  float* hn   = (float*)d_out + (size_t)NB * T * 128;

  for (int l = 0; l < 3; l++) {
    int blocks = (loOff[l] + 255) / 256;
    for (int q = 0; q < 4; q++) {
      const float* m = (q < 2) ? (const float*)d_in[maskIdx[l]] : nullptr;
      pack_w<<<blocks, 256, 0, stream>>>((const float*)d_in[wIdx[l] + q], m, wf[l][q],
                                         loOff[l], NNs[l], ITs[l], NTs[l], KBs[l],
                                         POLDs[l], OLDLENs[l], SOFFs[l], NEWLENs[l]);
    }
  }
  pack_w<<<(wfcLo + 255) / 256, 256, 0, stream>>>(Wfc, nullptr, wfc_f, wfcLo,
                                                  128, 128, 8, 4, 0, 0, 0, 128);

  hipMemsetAsync(bar, 0, NCH * T * 3 * sizeof(int), stream);
  h_scatter<<<(NB * HS + 255) / 256, 256, 0, stream>>>((const float*)d_in[1], hb0);

  PParams p;
  p.x = (const float*)d_in[0];
  p.h0 = hb0; p.h1 = hb1;
  for (int q = 0; q < 4; q++) {
    p.wf0[q] = wf[0][q]; p.wf1[q] = wf[1][q]; p.wf2[q] = wf[2][q];
    p.bias0[q] = (const float*)d_in[7 + q];
    p.bias1[q] = (const float*)d_in[16 + q];
    p.bias2[q] = (const float*)d_in[25 + q];
  }
  p.loOff0 = loOff[0]; p.loOff1 = loOff[1]; p.loOff2 = loOff[2];
  p.pred = pred;
  p.bar = bar;

  cfc_persistent<<<NCH * CBLK, 256, 0, stream>>>(p);

  final_linear<<<(NB * T) / 64, 256, 0, stream>>>(pred, wfc_f, wfcLo, bfc);
  h_gather<<<(NB * 1024 + 255) / 256, 256, 0, stream>>>(hb0, hn);
}